// Round 16
// baseline (811.124 us; speedup 1.0000x reference)
//
#include <hip/hip_runtime.h>
#include <hip/hip_bf16.h>
#include <math.h>
#include <limits.h>

#define N_PTSC 131072
#define NSHIFT 17
#define GD 14
#define FEAT 128
#define HIDN 64
#define TBITS 19
#define TSIZE (1<<TBITS)
#define EMPTY_KEY (-1)
#define VOXEL 0.05f
#define EPSC 1e-5f
#define RED_BLOCKS 256
#define NBUCK 16384
#define CONV_TV 256
#define NB_CONV (N_PTSC/CONV_TV)

typedef __attribute__((ext_vector_type(8))) short short8;
typedef __attribute__((ext_vector_type(4))) float f32x4;

// ---------------- workspace layout (bytes) ----------------
#define OFF_HDR   0
#define OFF_BNS   4096
#define OFF_BNQ   6144
#define OFF_RED   8192
#define OFF_HIST  16384
#define OFF_TKEY  (OFF_HIST + (size_t)NBUCK*4)
#define OFF_TSLOT (OFF_TKEY + (size_t)TSIZE*4)
#define OFF_TIDX  (OFF_TSLOT + (size_t)TSIZE*4)
#define OFF_INV   (OFF_TIDX + (size_t)N_PTSC*4)
#define OFF_VOXH  (OFF_INV + (size_t)N_PTSC*4)
#define OFF_CNT   (OFF_VOXH + (size_t)N_PTSC*4)
#define OFF_VC    (OFF_CNT + (size_t)N_PTSC*4)
#define OFF_NBR   (OFF_VC + (size_t)N_PTSC*12)
#define OFF_WT    (OFF_NBR + (size_t)N_PTSC*27*4)
#define OFF_XBF   (OFF_WT + (size_t)4*27*FEAT*FEAT*2)
#define OFF_VF    (OFF_XBF + (size_t)N_PTSC*FEAT*2)
#define OFF_YB    (OFF_VF + (size_t)N_PTSC*FEAT*4)
#define WS_NEED   (OFF_YB + (size_t)N_PTSC*FEAT*4)

__device__ __forceinline__ float cleanf(float x){
  if(__builtin_isnan(x)) return 0.f;
  if(__builtin_isinf(x)) return x>0.f?1.f:-1.f;
  return x;
}
__device__ __forceinline__ float get_ps(const float* p){
  float v=p[0];
  return (__builtin_isfinite(v) && v!=0.f) ? v : 1.f;
}
__device__ __forceinline__ unsigned hashh(int h){
  return ((unsigned)h*2654435761u)>>(32-TBITS);
}
__device__ __forceinline__ unsigned short f2bf(float x){
  __hip_bfloat16 h=__float2bfloat16(x);
  return *reinterpret_cast<unsigned short*>(&h);
}
__device__ __forceinline__ float bf2f(unsigned short u){
  unsigned v=((unsigned)u)<<16;
  float f;
  __builtin_memcpy(&f,&v,4);
  return f;
}
// async global->LDS 16B: per-lane global src, wave-uniform LDS base (+lane*16)
__device__ __forceinline__ void gld16(const void* g, void* l){
  __builtin_amdgcn_global_load_lds(
    (const __attribute__((address_space(1))) unsigned int*)g,
    (__attribute__((address_space(3))) unsigned int*)l, 16, 0, 0);
}

// ---------------- mean reduction ----------------
__global__ __launch_bounds__(256) void k_red1(const float* __restrict__ gp, const float* __restrict__ psin,
                                              double* __restrict__ redp){
  float ps=get_ps(psin);
  int tid=threadIdx.x;
  double s0=0,s1=0,s2=0;
  for(int i=blockIdx.x*256+tid; i<N_PTSC; i+=RED_BLOCKS*256){
    const float* g=gp+(size_t)i*GD;
    s0+=(double)(cleanf(g[0])/ps);
    s1+=(double)(cleanf(g[1])/ps);
    s2+=(double)(cleanf(g[2])/ps);
  }
  __shared__ double sm[3][256];
  sm[0][tid]=s0; sm[1][tid]=s1; sm[2][tid]=s2;
  __syncthreads();
  for(int s=128;s>0;s>>=1){
    if(tid<s){ sm[0][tid]+=sm[0][tid+s]; sm[1][tid]+=sm[1][tid+s]; sm[2][tid]+=sm[2][tid+s]; }
    __syncthreads();
  }
  if(tid==0){ redp[blockIdx.x*3+0]=sm[0][0]; redp[blockIdx.x*3+1]=sm[1][0]; redp[blockIdx.x*3+2]=sm[2][0]; }
}

__global__ __launch_bounds__(256) void k_red2(const double* __restrict__ redp, int* __restrict__ hi, float* __restrict__ hf){
  int tid=threadIdx.x;
  __shared__ double sm[3][256];
  sm[0][tid]=redp[tid*3+0]; sm[1][tid]=redp[tid*3+1]; sm[2][tid]=redp[tid*3+2];
  __syncthreads();
  for(int s=128;s>0;s>>=1){
    if(tid<s){ sm[0][tid]+=sm[0][tid+s]; sm[1][tid]+=sm[1][tid+s]; sm[2][tid]+=sm[2][tid+s]; }
    __syncthreads();
  }
  if(tid==0){
    hf[16]=(float)(sm[0][0]/(double)N_PTSC);
    hf[17]=(float)(sm[1][0]/(double)N_PTSC);
    hf[18]=(float)(sm[2][0]/(double)N_PTSC);
    hi[0]=INT_MAX; hi[1]=INT_MAX; hi[2]=INT_MAX;
    hi[3]=INT_MIN; hi[4]=INT_MIN; hi[5]=INT_MIN;
    hi[10]=0;
  }
}

// ---------------- voxel coords + extents ----------------
__global__ __launch_bounds__(256) void k_vc(const float* __restrict__ gp, const float* __restrict__ psin,
                                            const float* __restrict__ hf, int* __restrict__ hi, int* __restrict__ vc){
  float ps=get_ps(psin);
  float m0=hf[16], m1=hf[17], m2=hf[18];
  int mn0=INT_MAX,mn1=INT_MAX,mn2=INT_MAX,mx0=INT_MIN,mx1=INT_MIN,mx2=INT_MIN;
  for(int i=blockIdx.x*blockDim.x+threadIdx.x; i<N_PTSC; i+=gridDim.x*blockDim.x){
    const float* g=gp+(size_t)i*GD;
    int v0=(int)floorf((cleanf(g[0])/ps - m0)/VOXEL);
    int v1=(int)floorf((cleanf(g[1])/ps - m1)/VOXEL);
    int v2=(int)floorf((cleanf(g[2])/ps - m2)/VOXEL);
    vc[i]=v0; vc[N_PTSC+i]=v1; vc[2*N_PTSC+i]=v2;
    mn0=min(mn0,v0); mn1=min(mn1,v1); mn2=min(mn2,v2);
    mx0=max(mx0,v0); mx1=max(mx1,v1); mx2=max(mx2,v2);
  }
  __shared__ int sb[6][256];
  int tid=threadIdx.x;
  sb[0][tid]=mn0; sb[1][tid]=mn1; sb[2][tid]=mn2;
  sb[3][tid]=mx0; sb[4][tid]=mx1; sb[5][tid]=mx2;
  __syncthreads();
  for(int s=128;s>0;s>>=1){
    if(tid<s){
      #pragma unroll
      for(int d=0;d<3;d++){
        sb[d][tid]=min(sb[d][tid],sb[d][tid+s]);
        sb[3+d][tid]=max(sb[3+d][tid],sb[3+d][tid+s]);
      }
    }
    __syncthreads();
  }
  if(tid==0){
    atomicMin(&hi[0],sb[0][0]); atomicMin(&hi[1],sb[1][0]); atomicMin(&hi[2],sb[2][0]);
    atomicMax(&hi[3],sb[3][0]); atomicMax(&hi[4],sb[4][0]); atomicMax(&hi[5],sb[5][0]);
  }
}

__global__ void k_grid(int* hi){
  if(threadIdx.x==0&&blockIdx.x==0){
    int mx0=hi[3]-hi[0]+1, mx1=hi[4]-hi[1]+1, mx2=hi[5]-hi[2]+1;
    hi[6]=mx0; hi[7]=mx1; hi[8]=mx2; hi[9]=mx1*mx2;
    int hmax=mx0*mx1*mx2;
    int sh=0;
    while((hmax>>sh)>=NBUCK) sh++;
    hi[11]=sh;
  }
}

// ---------------- hash insert ----------------
__global__ __launch_bounds__(256) void k_hash(const int* __restrict__ vc, const int* __restrict__ hi,
                                              int* __restrict__ tkeys, int* __restrict__ tidx){
  int i=blockIdx.x*256+threadIdx.x;
  if(i>=N_PTSC) return;
  int mn0=hi[0],mn1=hi[1],mn2=hi[2],mx2=hi[8],m12=hi[9];
  int h=(vc[i]-mn0)*m12 + (vc[N_PTSC+i]-mn1)*mx2 + (vc[2*N_PTSC+i]-mn2);
  unsigned idx=hashh(h);
  while(true){
    int k=atomicCAS(&tkeys[idx],EMPTY_KEY,h);
    if(k==EMPTY_KEY||k==h) break;
    idx=(idx+1)&(TSIZE-1);
  }
  tidx[i]=(int)idx;
}

// ---------------- spatial slot assignment: bucketed counting sort on h ----------------
__global__ __launch_bounds__(256) void k_hist(const int* __restrict__ tkeys, const int* __restrict__ hi,
                                              int* __restrict__ hist){
  int t=blockIdx.x*256+threadIdx.x;
  if(t>=TSIZE) return;
  int k=tkeys[t];
  if(k!=EMPTY_KEY) atomicAdd(&hist[k>>hi[11]],1);
}

__global__ __launch_bounds__(256) void k_scan(int* __restrict__ hist, int* __restrict__ hi){
  __shared__ int psum[256];
  int tid=threadIdx.x;
  int base=tid*(NBUCK/256);
  int s=0;
  for(int i=0;i<NBUCK/256;i++) s+=hist[base+i];
  psum[tid]=s;
  __syncthreads();
  for(int off=1;off<256;off<<=1){
    int v=(tid>=off)?psum[tid-off]:0;
    __syncthreads();
    psum[tid]+=v;
    __syncthreads();
  }
  int run=psum[tid]-s;
  for(int i=0;i<NBUCK/256;i++){
    int v=hist[base+i];
    hist[base+i]=run;
    run+=v;
  }
  if(tid==255) hi[10]=run;
}

__global__ __launch_bounds__(256) void k_slot2(const int* __restrict__ tkeys, const int* __restrict__ hi,
                                               int* __restrict__ hist, int* __restrict__ tslot,
                                               int* __restrict__ voxh){
  int t=blockIdx.x*256+threadIdx.x;
  if(t>=TSIZE) return;
  int k=tkeys[t];
  if(k==EMPTY_KEY) return;
  int s=atomicAdd(&hist[k>>hi[11]],1);
  tslot[t]=s;
  voxh[s]=k;
}

// ---------------- weight prep: transpose + bf16, SWIZZLE BAKED INTO GLOBAL LAYOUT ----------------
// wt[lc][k] is 2048 granules of 8 bf16; granule q holds original (col=q>>4,
// sub=(q&15)^(col&15)) of W^T[o=col][i=sub*8+j] — so a LINEAR global_load_lds of this
// buffer reproduces exactly the old swizzled LDS image (B-read addressing unchanged).
__global__ __launch_bounds__(256) void k_wprep(const float* __restrict__ w1, const float* __restrict__ w2,
                                               unsigned short* __restrict__ wt){
  int t=blockIdx.x*256+threadIdx.x;
  int j=t&7, q=(t>>3)&2047, r=t>>14;
  int k=r%27, lc=r/27;
  int l=lc>>1, c=lc&1;
  int o=q>>4;
  int sub=(q&15)^(o&15);
  int i=sub*8+j;
  const float* src=(c==0)?w1:w2;
  wt[t]=f2bf(src[(((size_t)l*27+k)*128+i)*128+o]);
}

// ---------------- input encoder + LN + ReLU + mean-pool (wave per point) ----------------
__global__ __launch_bounds__(256) void k_pool(const float* __restrict__ gp,
    const float* __restrict__ w_in, const float* __restrict__ b_in,
    const float* __restrict__ ln_g, const float* __restrict__ ln_b,
    const int* __restrict__ tidx, const int* __restrict__ tslot,
    int* __restrict__ inv, int* __restrict__ cnt, float* __restrict__ vf){
  int p=blockIdx.x*4+(threadIdx.x>>6);
  int l=threadIdx.x&63;
  float x[GD];
  #pragma unroll
  for(int j=0;j<GD;j++) x[j]=cleanf(gp[(size_t)p*GD+j]);
  float a0=b_in[l], a1=b_in[l+64];
  #pragma unroll
  for(int j=0;j<GD;j++){
    a0=fmaf(x[j], w_in[j*FEAT+l], a0);
    a1=fmaf(x[j], w_in[j*FEAT+64+l], a1);
  }
  float s=a0+a1;
  #pragma unroll
  for(int off=32;off>0;off>>=1) s+=__shfl_xor(s,off);
  float mu=s*(1.f/FEAT);
  float d0=a0-mu, d1=a1-mu;
  float q=d0*d0+d1*d1;
  #pragma unroll
  for(int off=32;off>0;off>>=1) q+=__shfl_xor(q,off);
  float rs=rsqrtf(q*(1.f/FEAT)+EPSC);
  float y0=fmaxf(d0*rs*ln_g[l]+ln_b[l],0.f);
  float y1=fmaxf(d1*rs*ln_g[64+l]+ln_b[64+l],0.f);
  int slot=tslot[tidx[p]];
  if(l==0){ inv[p]=slot; atomicAdd(&cnt[slot],1); }
  atomicAdd(&vf[(size_t)slot*FEAT+l], y0);
  atomicAdd(&vf[(size_t)slot*FEAT+64+l], y1);
}

__global__ __launch_bounds__(256) void k_div(float* __restrict__ vf, unsigned short* __restrict__ xbf,
                                             const int* __restrict__ cnt, const int* __restrict__ hi){
  int M=hi[10];
  int total=M*FEAT;
  for(int i=blockIdx.x*blockDim.x+threadIdx.x; i<total; i+=gridDim.x*blockDim.x){
    int slot=i>>7;
    float v=vf[i]/(float)max(cnt[slot],1);
    vf[i]=v;
    xbf[i]=f2bf(v);
  }
}

// ---------------- neighbor table, tap-major: nbr[k<<17 | slot] ----------------
__global__ __launch_bounds__(256) void k_nbr(const int* __restrict__ voxh, const int* __restrict__ tkeys,
                                             const int* __restrict__ tslot, const int* __restrict__ hi,
                                             int* __restrict__ nbr){
  int M=hi[10];
  int mx0=hi[6],mx1=hi[7],mx2=hi[8],m12=hi[9];
  int total=27<<NSHIFT;
  for(int i=blockIdx.x*blockDim.x+threadIdx.x; i<total; i+=gridDim.x*blockDim.x){
    int s=i&(N_PTSC-1), k=i>>NSHIFT;
    if(s>=M) continue;
    int h=voxh[s];
    int c0=h/m12; int r=h-c0*m12; int c1=r/mx2; int c2=r-c1*mx2;
    int n0=c0+k/9-1, n1=c1+(k/3)%3-1, n2=c2+k%3-1;
    int res=-1;
    if(n0>=0&&n0<mx0&&n1>=0&&n1<mx1&&n2>=0&&n2<mx2){
      int nh=n0*m12+n1*mx2+n2;
      unsigned idx=hashh(nh);
      while(true){
        int kk=tkeys[idx];
        if(kk==nh){ res=tslot[idx]; break; }
        if(kk==EMPTY_KEY) break;
        idx=(idx+1)&(TSIZE-1);
      }
    }
    nbr[i]=res;
  }
}

// ---------------- submanifold conv: MFMA, async global_load_lds W-dbuf, staged bf16 Y ----------------
// R12's proven 32x128 wave geometry + epilogue. W staging via
// __builtin_amdgcn_global_load_lds width=16 (pre-swizzled wt, linear LDS dest):
// no wreg round-trip, no ds_writes, no staging address VALU. Per-tap __syncthreads()
// drains vmcnt before the buffer is consumed.
__global__ __launch_bounds__(512,4) void k_conv(const unsigned short* __restrict__ X,
      unsigned short* __restrict__ Y, const unsigned short* __restrict__ Wt,
      const int* __restrict__ nbr, const int* __restrict__ hi,
      float* __restrict__ bnsum, float* __restrict__ bnsq){
  int M=hi[10];
  int bid=blockIdx.x;
  int swz=(bid&7)*(NB_CONV>>3)+(bid>>3);
  int v0=swz*CONV_TV;
  if(v0>=M) return;
  __shared__ __align__(16) char smem[69632];   // Ws[2][16384]us (64KB) | St f32[256][68] (68KB)
  __shared__ float bsum[FEAT], bsq[FEAT];
  unsigned short (*Ws)[FEAT*FEAT]=(unsigned short(*)[FEAT*FEAT])smem;
  int tid=threadIdx.x;
  int wid=tid>>6, l=tid&63;
  int g=l>>4, ln=l&15;
  int rbase=v0+wid*32;
  f32x4 acc[2][8];
  #pragma unroll
  for(int rt=0;rt<2;rt++)
    #pragma unroll
    for(int nt=0;nt<8;nt++)
      acc[rt][nt]=(f32x4){0.f,0.f,0.f,0.f};
  short8 zf={0,0,0,0,0,0,0,0};
  if(tid<FEAT){ bsum[tid]=0.f; bsq[tid]=0.f; }
  // stage W[0] -> Ws[0] via async global_load_lds (pre-swizzled, linear)
  #pragma unroll
  for(int j=0;j<4;j++)
    gld16(Wt+(size_t)(j*512+tid)*8, &Ws[0][(size_t)(j*512+wid*64)*8]);
  int nbc[2];
  #pragma unroll
  for(int rt=0;rt<2;rt++){
    int r=rbase+rt*16+ln;
    nbc[rt]=(r<M)?nbr[r]:-1;
  }
  int cur=0;
  for(int k=0;k<27;k++){
    __syncthreads();   // drains vmcnt: Ws[cur] complete; Ws[cur^1] free
    int nbn[2];
    if(k<26){
      const unsigned short* wk=Wt+(size_t)(k+1)*FEAT*FEAT;
      #pragma unroll
      for(int j=0;j<4;j++)
        gld16(wk+(size_t)(j*512+tid)*8, &Ws[cur^1][(size_t)(j*512+wid*64)*8]);
      int kb=(k+1)<<NSHIFT;
      #pragma unroll
      for(int rt=0;rt<2;rt++){
        int r=rbase+rt*16+ln;
        nbn[rt]=(r<M)?nbr[kb+r]:-1;
      }
    }
    unsigned rtm=0;
    #pragma unroll
    for(int rt=0;rt<2;rt++) if(__ballot(nbc[rt]>=0)) rtm|=1u<<rt;
    if(rtm){
      #pragma unroll
      for(int ks=0;ks<4;ks++){
        short8 a[2];
        #pragma unroll
        for(int rt=0;rt<2;rt++){
          a[rt]=zf;
          if(nbc[rt]>=0) a[rt]=*(const short8*)(X+(size_t)nbc[rt]*FEAT+ks*32+g*8);
        }
        #pragma unroll
        for(int nt=0;nt<8;nt++){
          int col=nt*16+ln;
          short8 b=*(const short8*)&Ws[cur][(size_t)(col*16+((ks*4+g)^ln))*8];
          #pragma unroll
          for(int rt=0;rt<2;rt++)
            if((rtm>>rt)&1u)
              acc[rt][nt]=__builtin_amdgcn_mfma_f32_16x16x32_bf16(a[rt],b,acc[rt][nt],0,0,0);
        }
      }
    }
    if(k<26){
      #pragma unroll
      for(int rt=0;rt<2;rt++) nbc[rt]=nbn[rt];
      cur^=1;
    }
  }
  // ---- BN partial sums from exact f32 acc ----
  #pragma unroll
  for(int nt=0;nt<8;nt++){
    int col=nt*16+ln;
    float s=0.f,q=0.f;
    #pragma unroll
    for(int rt=0;rt<2;rt++){
      int vb=rbase+rt*16+g*4;
      #pragma unroll
      for(int r=0;r<4;r++){
        if(vb+r<M){
          float val=acc[rt][nt][r];
          s+=val; q+=val*val;
        }
      }
    }
    s+=__shfl_xor(s,16); s+=__shfl_xor(s,32);
    q+=__shfl_xor(q,16); q+=__shfl_xor(q,32);
    if(g==0){ atomicAdd(&bsum[col],s); atomicAdd(&bsq[col],q); }
  }
  // ---- staged Y write: two LITERAL halves through f32 LDS ----
  float* St=(float*)smem;   // [256][68] f32
  __syncthreads();          // all Ws reads complete; smem reusable
  // ===== half 0: nt 0..3 -> Y cols 0..63 =====
  #pragma unroll
  for(int nt4=0;nt4<4;nt4++){
    int col=nt4*16+ln;
    #pragma unroll
    for(int rt=0;rt<2;rt++){
      float* dst=&St[(size_t)(wid*32+rt*16+g*4)*68+col];
      dst[0]  =acc[rt][nt4][0];
      dst[68] =acc[rt][nt4][1];
      dst[136]=acc[rt][nt4][2];
      dst[204]=acc[rt][nt4][3];
    }
  }
  __syncthreads();
  #pragma unroll 1
  for(int j=0;j<8;j++){
    int c=j*512+tid;
    int row=c>>4, off=c&15;
    int grow=v0+row;
    if(grow<M){
      float4 vv=*(const float4*)&St[(size_t)row*68+off*4];
      uint2 pk;
      pk.x=(unsigned)f2bf(vv.x)|((unsigned)f2bf(vv.y)<<16);
      pk.y=(unsigned)f2bf(vv.z)|((unsigned)f2bf(vv.w)<<16);
      *(uint2*)(Y+(size_t)grow*FEAT+off*4)=pk;
    }
  }
  __syncthreads();
  // ===== half 1: nt 4..7 -> Y cols 64..127 =====
  #pragma unroll
  for(int nt4=0;nt4<4;nt4++){
    int col=nt4*16+ln;
    #pragma unroll
    for(int rt=0;rt<2;rt++){
      float* dst=&St[(size_t)(wid*32+rt*16+g*4)*68+col];
      dst[0]  =acc[rt][nt4+4][0];
      dst[68] =acc[rt][nt4+4][1];
      dst[136]=acc[rt][nt4+4][2];
      dst[204]=acc[rt][nt4+4][3];
    }
  }
  __syncthreads();
  #pragma unroll 1
  for(int j=0;j<8;j++){
    int c=j*512+tid;
    int row=c>>4, off=c&15;
    int grow=v0+row;
    if(grow<M){
      float4 vv=*(const float4*)&St[(size_t)row*68+off*4];
      uint2 pk;
      pk.x=(unsigned)f2bf(vv.x)|((unsigned)f2bf(vv.y)<<16);
      pk.y=(unsigned)f2bf(vv.z)|((unsigned)f2bf(vv.w)<<16);
      *(uint2*)(Y+(size_t)grow*FEAT+64+off*4)=pk;
    }
  }
  __syncthreads();
  if(tid<FEAT){
    atomicAdd(&bnsum[tid],bsum[tid]);
    atomicAdd(&bnsq[tid],bsq[tid]);
  }
}

// ---------------- BN finish + apply (vectorized, bf16 Y input) ----------------
__global__ __launch_bounds__(256) void k_bnapply_relu(const unsigned short* __restrict__ ybf, unsigned short* __restrict__ xbf,
      const float* __restrict__ bnsum, const float* __restrict__ bnsq,
      const float* __restrict__ bng, const float* __restrict__ bnb, const int* __restrict__ hi){
  __shared__ float ssc[FEAT], sof[FEAT];
  int M=hi[10];
  if(threadIdx.x<FEAT){
    double Md=(double)(M>0?M:1);
    double mu=(double)bnsum[threadIdx.x]/Md;
    double var=(double)bnsq[threadIdx.x]/Md-mu*mu;
    if(var<0.0) var=0.0;
    float sc=(float)(1.0/sqrt(var+(double)EPSC))*bng[threadIdx.x];
    ssc[threadIdx.x]=sc;
    sof[threadIdx.x]=bnb[threadIdx.x]-(float)mu*sc;
  }
  __syncthreads();
  int total=M*16;
  for(int i=blockIdx.x*blockDim.x+threadIdx.x; i<total; i+=gridDim.x*blockDim.x){
    int c0=(i&15)*8;
    short8 yv=*(const short8*)(ybf+(size_t)i*8);
    short8 ov;
    #pragma unroll
    for(int j=0;j<8;j++){
      float v=bf2f((unsigned short)yv[j]);
      ov[j]=(short)f2bf(fmaxf(fmaf(v,ssc[c0+j],sof[c0+j]),0.f));
    }
    *(short8*)(xbf+(size_t)i*8)=ov;
  }
}

__global__ __launch_bounds__(256) void k_bnapply_res(const unsigned short* __restrict__ ybf, float* __restrict__ vf,
      unsigned short* __restrict__ xbf,
      const float* __restrict__ bnsum, const float* __restrict__ bnsq,
      const float* __restrict__ bng, const float* __restrict__ bnb, const int* __restrict__ hi){
  __shared__ float ssc[FEAT], sof[FEAT];
  int M=hi[10];
  if(threadIdx.x<FEAT){
    double Md=(double)(M>0?M:1);
    double mu=(double)bnsum[threadIdx.x]/Md;
    double var=(double)bnsq[threadIdx.x]/Md-mu*mu;
    if(var<0.0) var=0.0;
    float sc=(float)(1.0/sqrt(var+(double)EPSC))*bng[threadIdx.x];
    ssc[threadIdx.x]=sc;
    sof[threadIdx.x]=bnb[threadIdx.x]-(float)mu*sc;
  }
  __syncthreads();
  int total=M*16;
  for(int i=blockIdx.x*blockDim.x+threadIdx.x; i<total; i+=gridDim.x*blockDim.x){
    int c0=(i&15)*8;
    short8 yv=*(const short8*)(ybf+(size_t)i*8);
    float4 v0=*(const float4*)(vf+(size_t)i*8);
    float4 v1=*(const float4*)(vf+(size_t)i*8+4);
    float rv[8]={v0.x,v0.y,v0.z,v0.w,v1.x,v1.y,v1.z,v1.w};
    float nv[8];
    #pragma unroll
    for(int j=0;j<8;j++){
      float v=bf2f((unsigned short)yv[j]);
      nv[j]=fmaxf(fmaf(v,ssc[c0+j],sof[c0+j])+rv[j],0.f);
    }
    short8 ov;
    #pragma unroll
    for(int j=0;j<8;j++) ov[j]=(short)f2bf(nv[j]);
    *(float4*)(vf+(size_t)i*8)=make_float4(nv[0],nv[1],nv[2],nv[3]);
    *(float4*)(vf+(size_t)i*8+4)=make_float4(nv[4],nv[5],nv[6],nv[7]);
    *(short8*)(xbf+(size_t)i*8)=ov;
  }
}

// ---------------- output head: MFMA GEMM1 (128->64) + scalar GEMM2 (64->14) ----------------
__global__ __launch_bounds__(256) void k_headm(const unsigned short* __restrict__ X, const int* __restrict__ inv,
    const float* __restrict__ w1, const float* __restrict__ b1,
    const float* __restrict__ w2, const float* __restrict__ b2, float* __restrict__ out){
  __shared__ unsigned short w1t[HIDN*FEAT];
  __shared__ float hbuf[FEAT*65];
  __shared__ float w2s[HIDN*GD];
  __shared__ float b1s[HIDN];
  int tid=threadIdx.x;
  for(int e=tid;e<HIDN*FEAT;e+=256){
    int o=e>>7, in=e&127;
    int sub=in>>3, j=in&7;
    w1t[(o*16+(sub^(o&15)))*8+j]=f2bf(w1[in*HIDN+o]);
  }
  for(int i=tid;i<HIDN*GD;i+=256) w2s[i]=w2[i];
  if(tid<HIDN) b1s[tid]=b1[tid];
  __syncthreads();
  int p0=blockIdx.x*128;
  int w=tid>>6, l=tid&63;
  int g=l>>4, ln=l&15;
  int rbase=w*32;
  int gr[2];
  #pragma unroll
  for(int rt=0;rt<2;rt++) gr[rt]=inv[p0+rbase+rt*16+ln];
  f32x4 acc[2][4];
  #pragma unroll
  for(int rt=0;rt<2;rt++)
    #pragma unroll
    for(int nt=0;nt<4;nt++)
      acc[rt][nt]=(f32x4){0.f,0.f,0.f,0.f};
  #pragma unroll
  for(int ks=0;ks<4;ks++){
    short8 a[2];
    #pragma unroll
    for(int rt=0;rt<2;rt++)
      a[rt]=*(const short8*)(X+(size_t)gr[rt]*FEAT+ks*32+g*8);
    #pragma unroll
    for(int nt=0;nt<4;nt++){
      int col=nt*16+ln;
      short8 b=*(const short8*)&w1t[(size_t)(col*16+((ks*4+g)^(col&15)))*8];
      #pragma unroll
      for(int rt=0;rt<2;rt++)
        acc[rt][nt]=__builtin_amdgcn_mfma_f32_16x16x32_bf16(a[rt],b,acc[rt][nt],0,0,0);
    }
  }
  #pragma unroll
  for(int rt=0;rt<2;rt++){
    #pragma unroll
    for(int nt=0;nt<4;nt++){
      int col=nt*16+ln;
      float bb=b1s[col];
      #pragma unroll
      for(int r=0;r<4;r++){
        int row=rbase+rt*16+g*4+r;
        hbuf[row*65+col]=fmaxf(acc[rt][nt][r]+bb,0.f);
      }
    }
  }
  __syncthreads();
  int row=tid>>1, o0=(tid&1)*7;
  float a2[7];
  #pragma unroll
  for(int oi=0;oi<7;oi++) a2[oi]=b2[o0+oi];
  const float* hr=&hbuf[row*65];
  for(int j=0;j<HIDN;j++){
    float hv=hr[j];
    const float* wr=&w2s[j*GD+o0];
    #pragma unroll
    for(int oi=0;oi<7;oi++) a2[oi]=fmaf(hv,wr[oi],a2[oi]);
  }
  float* op=out+(size_t)(p0+row)*GD+o0;
  #pragma unroll
  for(int oi=0;oi<7;oi++) op[oi]=a2[oi];
}

extern "C" void kernel_launch(void* const* d_in, const int* in_sizes, int n_in,
                              void* d_out, int out_size, void* d_ws, size_t ws_size,
                              hipStream_t stream) {
  if(ws_size < WS_NEED) return;
  const float* gp  =(const float*)d_in[0];
  const float* psin=(const float*)d_in[1];
  const float* w_in=(const float*)d_in[2];
  const float* b_in=(const float*)d_in[3];
  const float* ln_g=(const float*)d_in[4];
  const float* ln_b=(const float*)d_in[5];
  const float* cw1 =(const float*)d_in[6];
  const float* bn1g=(const float*)d_in[7];
  const float* bn1b=(const float*)d_in[8];
  const float* cw2 =(const float*)d_in[9];
  const float* bn2g=(const float*)d_in[10];
  const float* bn2b=(const float*)d_in[11];
  const float* wh1 =(const float*)d_in[12];
  const float* bh1 =(const float*)d_in[13];
  const float* wh2 =(const float*)d_in[14];
  const float* bh2 =(const float*)d_in[15];
  float* out=(float*)d_out;

  char* ws=(char*)d_ws;
  int*    hi    =(int*)(ws+OFF_HDR);
  float*  hf    =(float*)(ws+OFF_HDR);
  float*  bnsA  =(float*)(ws+OFF_BNS);
  float*  bnqA  =(float*)(ws+OFF_BNQ);
  double* redp  =(double*)(ws+OFF_RED);
  int*    hist  =(int*)(ws+OFF_HIST);
  int*    tkeys =(int*)(ws+OFF_TKEY);
  int*    tslot =(int*)(ws+OFF_TSLOT);
  int*    tidx  =(int*)(ws+OFF_TIDX);
  int*    inv   =(int*)(ws+OFF_INV);
  int*    voxh  =(int*)(ws+OFF_VOXH);
  int*    cnt   =(int*)(ws+OFF_CNT);
  int*    vc    =(int*)(ws+OFF_VC);
  int*    nbr   =(int*)(ws+OFF_NBR);
  unsigned short* wt =(unsigned short*)(ws+OFF_WT);
  unsigned short* xbf=(unsigned short*)(ws+OFF_XBF);
  float*  vf    =(float*)(ws+OFF_VF);
  unsigned short* ybuf=(unsigned short*)(ws+OFF_YB);

  hipMemsetAsync(tkeys,0xFF,(size_t)TSIZE*4,stream);
  hipMemsetAsync(vf,0,(size_t)N_PTSC*FEAT*4,stream);
  hipMemsetAsync(cnt,0,(size_t)N_PTSC*4,stream);
  hipMemsetAsync(hist,0,(size_t)NBUCK*4,stream);
  hipMemsetAsync(ws+OFF_BNS,0,4096,stream);

  k_red1<<<RED_BLOCKS,256,0,stream>>>(gp,psin,redp);
  k_red2<<<1,256,0,stream>>>(redp,hi,hf);
  k_vc<<<256,256,0,stream>>>(gp,psin,hf,hi,vc);
  k_grid<<<1,64,0,stream>>>(hi);
  k_hash<<<N_PTSC/256,256,0,stream>>>(vc,hi,tkeys,tidx);
  k_hist<<<TSIZE/256,256,0,stream>>>(tkeys,hi,hist);
  k_scan<<<1,256,0,stream>>>(hist,hi);
  k_slot2<<<TSIZE/256,256,0,stream>>>(tkeys,hi,hist,tslot,voxh);
  k_wprep<<<(4*27*FEAT*FEAT)/256,256,0,stream>>>(cw1,cw2,wt);
  k_pool<<<N_PTSC/4,256,0,stream>>>(gp,w_in,b_in,ln_g,ln_b,tidx,tslot,inv,cnt,vf);
  k_div<<<2048,256,0,stream>>>(vf,xbf,cnt,hi);
  k_nbr<<<2048,256,0,stream>>>(voxh,tkeys,tslot,hi,nbr);

  for(int l=0;l<2;l++){
    int j0=l*2, j1=l*2+1;
    k_conv<<<NB_CONV,512,0,stream>>>(xbf,ybuf,wt+((size_t)j0*27)*FEAT*FEAT,nbr,hi,bnsA+j0*FEAT,bnqA+j0*FEAT);
    k_bnapply_relu<<<2048,256,0,stream>>>(ybuf,xbf,bnsA+j0*FEAT,bnqA+j0*FEAT,bn1g+(size_t)l*FEAT,bn1b+(size_t)l*FEAT,hi);

    k_conv<<<NB_CONV,512,0,stream>>>(xbf,ybuf,wt+((size_t)j1*27)*FEAT*FEAT,nbr,hi,bnsA+j1*FEAT,bnqA+j1*FEAT);
    k_bnapply_res<<<2048,256,0,stream>>>(ybuf,vf,xbf,bnsA+j1*FEAT,bnqA+j1*FEAT,bn2g+(size_t)l*FEAT,bn2b+(size_t)l*FEAT,hi);
  }

  k_headm<<<N_PTSC/128,256,0,stream>>>(xbf,inv,wh1,bh1,wh2,bh2,out);
}

// Round 17
// 787.802 us; speedup vs baseline: 1.0296x; 1.0296x over previous
//
#include <hip/hip_runtime.h>
#include <hip/hip_bf16.h>
#include <math.h>
#include <limits.h>

#define N_PTSC 131072
#define NSHIFT 17
#define GD 14
#define FEAT 128
#define HIDN 64
#define TBITS 19
#define TSIZE (1<<TBITS)
#define EMPTY_KEY (-1)
#define VOXEL 0.05f
#define EPSC 1e-5f
#define RED_BLOCKS 256
#define NBUCK 16384
#define CONV_TV 256
#define NB_CONV (N_PTSC/CONV_TV)

typedef __attribute__((ext_vector_type(8))) short short8;
typedef __attribute__((ext_vector_type(4))) float f32x4;

// ---------------- workspace layout (bytes) ----------------
#define OFF_HDR   0
#define OFF_BNS   4096
#define OFF_BNQ   6144
#define OFF_RED   8192
#define OFF_HIST  16384
#define OFF_TKEY  (OFF_HIST + (size_t)NBUCK*4)
#define OFF_TSLOT (OFF_TKEY + (size_t)TSIZE*4)
#define OFF_TIDX  (OFF_TSLOT + (size_t)TSIZE*4)
#define OFF_INV   (OFF_TIDX + (size_t)N_PTSC*4)
#define OFF_VOXH  (OFF_INV + (size_t)N_PTSC*4)
#define OFF_CNT   (OFF_VOXH + (size_t)N_PTSC*4)
#define OFF_VC    (OFF_CNT + (size_t)N_PTSC*4)
#define OFF_NBR   (OFF_VC + (size_t)N_PTSC*12)
#define OFF_WT    (OFF_NBR + (size_t)N_PTSC*27*4)
#define OFF_XBF   (OFF_WT + (size_t)4*27*FEAT*FEAT*2)
#define OFF_VF    (OFF_XBF + (size_t)N_PTSC*FEAT*2)
#define OFF_YB    (OFF_VF + (size_t)N_PTSC*FEAT*4)
#define OFF_RBF   (OFF_YB + (size_t)N_PTSC*FEAT*2)
#define WS_NEED   (OFF_RBF + (size_t)N_PTSC*FEAT*2)

__device__ __forceinline__ float cleanf(float x){
  if(__builtin_isnan(x)) return 0.f;
  if(__builtin_isinf(x)) return x>0.f?1.f:-1.f;
  return x;
}
__device__ __forceinline__ float get_ps(const float* p){
  float v=p[0];
  return (__builtin_isfinite(v) && v!=0.f) ? v : 1.f;
}
__device__ __forceinline__ unsigned hashh(int h){
  return ((unsigned)h*2654435761u)>>(32-TBITS);
}
__device__ __forceinline__ unsigned short f2bf(float x){
  __hip_bfloat16 h=__float2bfloat16(x);
  return *reinterpret_cast<unsigned short*>(&h);
}
__device__ __forceinline__ float bf2f(unsigned short u){
  unsigned v=((unsigned)u)<<16;
  float f;
  __builtin_memcpy(&f,&v,4);
  return f;
}
// async global->LDS 16B: per-lane global src, wave-uniform LDS base (+lane*16)
__device__ __forceinline__ void gld16(const void* g, void* l){
  __builtin_amdgcn_global_load_lds(
    (const __attribute__((address_space(1))) unsigned int*)g,
    (__attribute__((address_space(3))) unsigned int*)l, 16, 0, 0);
}

// ---------------- mean reduction ----------------
__global__ __launch_bounds__(256) void k_red1(const float* __restrict__ gp, const float* __restrict__ psin,
                                              double* __restrict__ redp){
  float ps=get_ps(psin);
  int tid=threadIdx.x;
  double s0=0,s1=0,s2=0;
  for(int i=blockIdx.x*256+tid; i<N_PTSC; i+=RED_BLOCKS*256){
    const float* g=gp+(size_t)i*GD;
    s0+=(double)(cleanf(g[0])/ps);
    s1+=(double)(cleanf(g[1])/ps);
    s2+=(double)(cleanf(g[2])/ps);
  }
  __shared__ double sm[3][256];
  sm[0][tid]=s0; sm[1][tid]=s1; sm[2][tid]=s2;
  __syncthreads();
  for(int s=128;s>0;s>>=1){
    if(tid<s){ sm[0][tid]+=sm[0][tid+s]; sm[1][tid]+=sm[1][tid+s]; sm[2][tid]+=sm[2][tid+s]; }
    __syncthreads();
  }
  if(tid==0){ redp[blockIdx.x*3+0]=sm[0][0]; redp[blockIdx.x*3+1]=sm[1][0]; redp[blockIdx.x*3+2]=sm[2][0]; }
}

__global__ __launch_bounds__(256) void k_red2(const double* __restrict__ redp, int* __restrict__ hi, float* __restrict__ hf){
  int tid=threadIdx.x;
  __shared__ double sm[3][256];
  sm[0][tid]=redp[tid*3+0]; sm[1][tid]=redp[tid*3+1]; sm[2][tid]=redp[tid*3+2];
  __syncthreads();
  for(int s=128;s>0;s>>=1){
    if(tid<s){ sm[0][tid]+=sm[0][tid+s]; sm[1][tid]+=sm[1][tid+s]; sm[2][tid]+=sm[2][tid+s]; }
    __syncthreads();
  }
  if(tid==0){
    hf[16]=(float)(sm[0][0]/(double)N_PTSC);
    hf[17]=(float)(sm[1][0]/(double)N_PTSC);
    hf[18]=(float)(sm[2][0]/(double)N_PTSC);
    hi[0]=INT_MAX; hi[1]=INT_MAX; hi[2]=INT_MAX;
    hi[3]=INT_MIN; hi[4]=INT_MIN; hi[5]=INT_MIN;
    hi[10]=0;
  }
}

// ---------------- voxel coords + extents ----------------
__global__ __launch_bounds__(256) void k_vc(const float* __restrict__ gp, const float* __restrict__ psin,
                                            const float* __restrict__ hf, int* __restrict__ hi, int* __restrict__ vc){
  float ps=get_ps(psin);
  float m0=hf[16], m1=hf[17], m2=hf[18];
  int mn0=INT_MAX,mn1=INT_MAX,mn2=INT_MAX,mx0=INT_MIN,mx1=INT_MIN,mx2=INT_MIN;
  for(int i=blockIdx.x*blockDim.x+threadIdx.x; i<N_PTSC; i+=gridDim.x*blockDim.x){
    const float* g=gp+(size_t)i*GD;
    int v0=(int)floorf((cleanf(g[0])/ps - m0)/VOXEL);
    int v1=(int)floorf((cleanf(g[1])/ps - m1)/VOXEL);
    int v2=(int)floorf((cleanf(g[2])/ps - m2)/VOXEL);
    vc[i]=v0; vc[N_PTSC+i]=v1; vc[2*N_PTSC+i]=v2;
    mn0=min(mn0,v0); mn1=min(mn1,v1); mn2=min(mn2,v2);
    mx0=max(mx0,v0); mx1=max(mx1,v1); mx2=max(mx2,v2);
  }
  __shared__ int sb[6][256];
  int tid=threadIdx.x;
  sb[0][tid]=mn0; sb[1][tid]=mn1; sb[2][tid]=mn2;
  sb[3][tid]=mx0; sb[4][tid]=mx1; sb[5][tid]=mx2;
  __syncthreads();
  for(int s=128;s>0;s>>=1){
    if(tid<s){
      #pragma unroll
      for(int d=0;d<3;d++){
        sb[d][tid]=min(sb[d][tid],sb[d][tid+s]);
        sb[3+d][tid]=max(sb[3+d][tid],sb[3+d][tid+s]);
      }
    }
    __syncthreads();
  }
  if(tid==0){
    atomicMin(&hi[0],sb[0][0]); atomicMin(&hi[1],sb[1][0]); atomicMin(&hi[2],sb[2][0]);
    atomicMax(&hi[3],sb[3][0]); atomicMax(&hi[4],sb[4][0]); atomicMax(&hi[5],sb[5][0]);
  }
}

__global__ void k_grid(int* hi){
  if(threadIdx.x==0&&blockIdx.x==0){
    int mx0=hi[3]-hi[0]+1, mx1=hi[4]-hi[1]+1, mx2=hi[5]-hi[2]+1;
    hi[6]=mx0; hi[7]=mx1; hi[8]=mx2; hi[9]=mx1*mx2;
    int hmax=mx0*mx1*mx2;
    int sh=0;
    while((hmax>>sh)>=NBUCK) sh++;
    hi[11]=sh;
  }
}

// ---------------- hash insert ----------------
__global__ __launch_bounds__(256) void k_hash(const int* __restrict__ vc, const int* __restrict__ hi,
                                              int* __restrict__ tkeys, int* __restrict__ tidx){
  int i=blockIdx.x*256+threadIdx.x;
  if(i>=N_PTSC) return;
  int mn0=hi[0],mn1=hi[1],mn2=hi[2],mx2=hi[8],m12=hi[9];
  int h=(vc[i]-mn0)*m12 + (vc[N_PTSC+i]-mn1)*mx2 + (vc[2*N_PTSC+i]-mn2);
  unsigned idx=hashh(h);
  while(true){
    int k=atomicCAS(&tkeys[idx],EMPTY_KEY,h);
    if(k==EMPTY_KEY||k==h) break;
    idx=(idx+1)&(TSIZE-1);
  }
  tidx[i]=(int)idx;
}

// ---------------- spatial slot assignment: bucketed counting sort on h ----------------
__global__ __launch_bounds__(256) void k_hist(const int* __restrict__ tkeys, const int* __restrict__ hi,
                                              int* __restrict__ hist){
  int t=blockIdx.x*256+threadIdx.x;
  if(t>=TSIZE) return;
  int k=tkeys[t];
  if(k!=EMPTY_KEY) atomicAdd(&hist[k>>hi[11]],1);
}

__global__ __launch_bounds__(256) void k_scan(int* __restrict__ hist, int* __restrict__ hi){
  __shared__ int psum[256];
  int tid=threadIdx.x;
  int base=tid*(NBUCK/256);
  int s=0;
  for(int i=0;i<NBUCK/256;i++) s+=hist[base+i];
  psum[tid]=s;
  __syncthreads();
  for(int off=1;off<256;off<<=1){
    int v=(tid>=off)?psum[tid-off]:0;
    __syncthreads();
    psum[tid]+=v;
    __syncthreads();
  }
  int run=psum[tid]-s;
  for(int i=0;i<NBUCK/256;i++){
    int v=hist[base+i];
    hist[base+i]=run;
    run+=v;
  }
  if(tid==255) hi[10]=run;
}

__global__ __launch_bounds__(256) void k_slot2(const int* __restrict__ tkeys, const int* __restrict__ hi,
                                               int* __restrict__ hist, int* __restrict__ tslot,
                                               int* __restrict__ voxh){
  int t=blockIdx.x*256+threadIdx.x;
  if(t>=TSIZE) return;
  int k=tkeys[t];
  if(k==EMPTY_KEY) return;
  int s=atomicAdd(&hist[k>>hi[11]],1);
  tslot[t]=s;
  voxh[s]=k;
}

// ---------------- weight prep: transpose + bf16, swizzle baked into global layout ----------------
__global__ __launch_bounds__(256) void k_wprep(const float* __restrict__ w1, const float* __restrict__ w2,
                                               unsigned short* __restrict__ wt){
  int t=blockIdx.x*256+threadIdx.x;
  int j=t&7, q=(t>>3)&2047, r=t>>14;
  int k=r%27, lc=r/27;
  int l=lc>>1, c=lc&1;
  int o=q>>4;
  int sub=(q&15)^(o&15);
  int i=sub*8+j;
  const float* src=(c==0)?w1:w2;
  wt[t]=f2bf(src[(((size_t)l*27+k)*128+i)*128+o]);
}

// ---------------- input encoder + LN + ReLU + mean-pool (wave per point) ----------------
__global__ __launch_bounds__(256) void k_pool(const float* __restrict__ gp,
    const float* __restrict__ w_in, const float* __restrict__ b_in,
    const float* __restrict__ ln_g, const float* __restrict__ ln_b,
    const int* __restrict__ tidx, const int* __restrict__ tslot,
    int* __restrict__ inv, int* __restrict__ cnt, float* __restrict__ vf){
  int p=blockIdx.x*4+(threadIdx.x>>6);
  int l=threadIdx.x&63;
  float x[GD];
  #pragma unroll
  for(int j=0;j<GD;j++) x[j]=cleanf(gp[(size_t)p*GD+j]);
  float a0=b_in[l], a1=b_in[l+64];
  #pragma unroll
  for(int j=0;j<GD;j++){
    a0=fmaf(x[j], w_in[j*FEAT+l], a0);
    a1=fmaf(x[j], w_in[j*FEAT+64+l], a1);
  }
  float s=a0+a1;
  #pragma unroll
  for(int off=32;off>0;off>>=1) s+=__shfl_xor(s,off);
  float mu=s*(1.f/FEAT);
  float d0=a0-mu, d1=a1-mu;
  float q=d0*d0+d1*d1;
  #pragma unroll
  for(int off=32;off>0;off>>=1) q+=__shfl_xor(q,off);
  float rs=rsqrtf(q*(1.f/FEAT)+EPSC);
  float y0=fmaxf(d0*rs*ln_g[l]+ln_b[l],0.f);
  float y1=fmaxf(d1*rs*ln_g[64+l]+ln_b[64+l],0.f);
  int slot=tslot[tidx[p]];
  if(l==0){ inv[p]=slot; atomicAdd(&cnt[slot],1); }
  atomicAdd(&vf[(size_t)slot*FEAT+l], y0);
  atomicAdd(&vf[(size_t)slot*FEAT+64+l], y1);
}

// mean-divide -> bf16 activation (xbf) + bf16 residual (rbf); vf not rewritten
__global__ __launch_bounds__(256) void k_div(const float* __restrict__ vf, unsigned short* __restrict__ xbf,
                                             unsigned short* __restrict__ rbf,
                                             const int* __restrict__ cnt, const int* __restrict__ hi){
  int M=hi[10];
  int total=M*FEAT;
  for(int i=blockIdx.x*blockDim.x+threadIdx.x; i<total; i+=gridDim.x*blockDim.x){
    int slot=i>>7;
    unsigned short b=f2bf(vf[i]/(float)max(cnt[slot],1));
    xbf[i]=b;
    rbf[i]=b;
  }
}

// ---------------- neighbor table, tap-major: nbr[k<<17 | slot] ----------------
__global__ __launch_bounds__(256) void k_nbr(const int* __restrict__ voxh, const int* __restrict__ tkeys,
                                             const int* __restrict__ tslot, const int* __restrict__ hi,
                                             int* __restrict__ nbr){
  int M=hi[10];
  int mx0=hi[6],mx1=hi[7],mx2=hi[8],m12=hi[9];
  int total=27<<NSHIFT;
  for(int i=blockIdx.x*blockDim.x+threadIdx.x; i<total; i+=gridDim.x*blockDim.x){
    int s=i&(N_PTSC-1), k=i>>NSHIFT;
    if(s>=M) continue;
    int h=voxh[s];
    int c0=h/m12; int r=h-c0*m12; int c1=r/mx2; int c2=r-c1*mx2;
    int n0=c0+k/9-1, n1=c1+(k/3)%3-1, n2=c2+k%3-1;
    int res=-1;
    if(n0>=0&&n0<mx0&&n1>=0&&n1<mx1&&n2>=0&&n2<mx2){
      int nh=n0*m12+n1*mx2+n2;
      unsigned idx=hashh(nh);
      while(true){
        int kk=tkeys[idx];
        if(kk==nh){ res=tslot[idx]; break; }
        if(kk==EMPTY_KEY) break;
        idx=(idx+1)&(TSIZE-1);
      }
    }
    nbr[i]=res;
  }
}

// ---------------- submanifold conv: MFMA, async global_load_lds W-dbuf, staged bf16 Y ----------------
__global__ __launch_bounds__(512,4) void k_conv(const unsigned short* __restrict__ X,
      unsigned short* __restrict__ Y, const unsigned short* __restrict__ Wt,
      const int* __restrict__ nbr, const int* __restrict__ hi,
      float* __restrict__ bnsum, float* __restrict__ bnsq){
  int M=hi[10];
  int bid=blockIdx.x;
  int swz=(bid&7)*(NB_CONV>>3)+(bid>>3);
  int v0=swz*CONV_TV;
  if(v0>=M) return;
  __shared__ __align__(16) char smem[69632];   // Ws[2][16384]us (64KB) | St f32[256][68] (68KB)
  __shared__ float bsum[FEAT], bsq[FEAT];
  unsigned short (*Ws)[FEAT*FEAT]=(unsigned short(*)[FEAT*FEAT])smem;
  int tid=threadIdx.x;
  int wid=tid>>6, l=tid&63;
  int g=l>>4, ln=l&15;
  int rbase=v0+wid*32;
  f32x4 acc[2][8];
  #pragma unroll
  for(int rt=0;rt<2;rt++)
    #pragma unroll
    for(int nt=0;nt<8;nt++)
      acc[rt][nt]=(f32x4){0.f,0.f,0.f,0.f};
  short8 zf={0,0,0,0,0,0,0,0};
  if(tid<FEAT){ bsum[tid]=0.f; bsq[tid]=0.f; }
  #pragma unroll
  for(int j=0;j<4;j++)
    gld16(Wt+(size_t)(j*512+tid)*8, &Ws[0][(size_t)(j*512+wid*64)*8]);
  int nbc[2];
  #pragma unroll
  for(int rt=0;rt<2;rt++){
    int r=rbase+rt*16+ln;
    nbc[rt]=(r<M)?nbr[r]:-1;
  }
  int cur=0;
  for(int k=0;k<27;k++){
    __syncthreads();
    int nbn[2];
    if(k<26){
      const unsigned short* wk=Wt+(size_t)(k+1)*FEAT*FEAT;
      #pragma unroll
      for(int j=0;j<4;j++)
        gld16(wk+(size_t)(j*512+tid)*8, &Ws[cur^1][(size_t)(j*512+wid*64)*8]);
      int kb=(k+1)<<NSHIFT;
      #pragma unroll
      for(int rt=0;rt<2;rt++){
        int r=rbase+rt*16+ln;
        nbn[rt]=(r<M)?nbr[kb+r]:-1;
      }
    }
    unsigned rtm=0;
    #pragma unroll
    for(int rt=0;rt<2;rt++) if(__ballot(nbc[rt]>=0)) rtm|=1u<<rt;
    if(rtm){
      #pragma unroll
      for(int ks=0;ks<4;ks++){
        short8 a[2];
        #pragma unroll
        for(int rt=0;rt<2;rt++){
          a[rt]=zf;
          if(nbc[rt]>=0) a[rt]=*(const short8*)(X+(size_t)nbc[rt]*FEAT+ks*32+g*8);
        }
        #pragma unroll
        for(int nt=0;nt<8;nt++){
          int col=nt*16+ln;
          short8 b=*(const short8*)&Ws[cur][(size_t)(col*16+((ks*4+g)^ln))*8];
          #pragma unroll
          for(int rt=0;rt<2;rt++)
            if((rtm>>rt)&1u)
              acc[rt][nt]=__builtin_amdgcn_mfma_f32_16x16x32_bf16(a[rt],b,acc[rt][nt],0,0,0);
        }
      }
    }
    if(k<26){
      #pragma unroll
      for(int rt=0;rt<2;rt++) nbc[rt]=nbn[rt];
      cur^=1;
    }
  }
  // BN partial sums from exact f32 acc
  #pragma unroll
  for(int nt=0;nt<8;nt++){
    int col=nt*16+ln;
    float s=0.f,q=0.f;
    #pragma unroll
    for(int rt=0;rt<2;rt++){
      int vb=rbase+rt*16+g*4;
      #pragma unroll
      for(int r=0;r<4;r++){
        if(vb+r<M){
          float val=acc[rt][nt][r];
          s+=val; q+=val*val;
        }
      }
    }
    s+=__shfl_xor(s,16); s+=__shfl_xor(s,32);
    q+=__shfl_xor(q,16); q+=__shfl_xor(q,32);
    if(g==0){ atomicAdd(&bsum[col],s); atomicAdd(&bsq[col],q); }
  }
  // staged Y write: two LITERAL halves through f32 LDS
  float* St=(float*)smem;
  __syncthreads();
  // half 0: nt 0..3 -> cols 0..63
  #pragma unroll
  for(int nt4=0;nt4<4;nt4++){
    int col=nt4*16+ln;
    #pragma unroll
    for(int rt=0;rt<2;rt++){
      float* dst=&St[(size_t)(wid*32+rt*16+g*4)*68+col];
      dst[0]  =acc[rt][nt4][0];
      dst[68] =acc[rt][nt4][1];
      dst[136]=acc[rt][nt4][2];
      dst[204]=acc[rt][nt4][3];
    }
  }
  __syncthreads();
  #pragma unroll 1
  for(int j=0;j<8;j++){
    int c=j*512+tid;
    int row=c>>4, off=c&15;
    int grow=v0+row;
    if(grow<M){
      float4 vv=*(const float4*)&St[(size_t)row*68+off*4];
      uint2 pk;
      pk.x=(unsigned)f2bf(vv.x)|((unsigned)f2bf(vv.y)<<16);
      pk.y=(unsigned)f2bf(vv.z)|((unsigned)f2bf(vv.w)<<16);
      *(uint2*)(Y+(size_t)grow*FEAT+off*4)=pk;
    }
  }
  __syncthreads();
  // half 1: nt 4..7 -> cols 64..127
  #pragma unroll
  for(int nt4=0;nt4<4;nt4++){
    int col=nt4*16+ln;
    #pragma unroll
    for(int rt=0;rt<2;rt++){
      float* dst=&St[(size_t)(wid*32+rt*16+g*4)*68+col];
      dst[0]  =acc[rt][nt4+4][0];
      dst[68] =acc[rt][nt4+4][1];
      dst[136]=acc[rt][nt4+4][2];
      dst[204]=acc[rt][nt4+4][3];
    }
  }
  __syncthreads();
  #pragma unroll 1
  for(int j=0;j<8;j++){
    int c=j*512+tid;
    int row=c>>4, off=c&15;
    int grow=v0+row;
    if(grow<M){
      float4 vv=*(const float4*)&St[(size_t)row*68+off*4];
      uint2 pk;
      pk.x=(unsigned)f2bf(vv.x)|((unsigned)f2bf(vv.y)<<16);
      pk.y=(unsigned)f2bf(vv.z)|((unsigned)f2bf(vv.w)<<16);
      *(uint2*)(Y+(size_t)grow*FEAT+64+off*4)=pk;
    }
  }
  __syncthreads();
  if(tid<FEAT){
    atomicAdd(&bnsum[tid],bsum[tid]);
    atomicAdd(&bnsq[tid],bsq[tid]);
  }
}

// ---------------- BN finish + apply (vectorized, bf16 Y input) ----------------
__global__ __launch_bounds__(256) void k_bnapply_relu(const unsigned short* __restrict__ ybf, unsigned short* __restrict__ xbf,
      const float* __restrict__ bnsum, const float* __restrict__ bnsq,
      const float* __restrict__ bng, const float* __restrict__ bnb, const int* __restrict__ hi){
  __shared__ float ssc[FEAT], sof[FEAT];
  int M=hi[10];
  if(threadIdx.x<FEAT){
    double Md=(double)(M>0?M:1);
    double mu=(double)bnsum[threadIdx.x]/Md;
    double var=(double)bnsq[threadIdx.x]/Md-mu*mu;
    if(var<0.0) var=0.0;
    float sc=(float)(1.0/sqrt(var+(double)EPSC))*bng[threadIdx.x];
    ssc[threadIdx.x]=sc;
    sof[threadIdx.x]=bnb[threadIdx.x]-(float)mu*sc;
  }
  __syncthreads();
  int total=M*16;
  for(int i=blockIdx.x*blockDim.x+threadIdx.x; i<total; i+=gridDim.x*blockDim.x){
    int c0=(i&15)*8;
    short8 yv=*(const short8*)(ybf+(size_t)i*8);
    short8 ov;
    #pragma unroll
    for(int j=0;j<8;j++){
      float v=bf2f((unsigned short)yv[j]);
      ov[j]=(short)f2bf(fmaxf(fmaf(v,ssc[c0+j],sof[c0+j]),0.f));
    }
    *(short8*)(xbf+(size_t)i*8)=ov;
  }
}

// BN + bf16 residual + ReLU -> xbf (and rbf unless LAST)
template<int LAST>
__global__ __launch_bounds__(256) void k_bnapply_res(const unsigned short* __restrict__ ybf,
      unsigned short* __restrict__ rbf, unsigned short* __restrict__ xbf,
      const float* __restrict__ bnsum, const float* __restrict__ bnsq,
      const float* __restrict__ bng, const float* __restrict__ bnb, const int* __restrict__ hi){
  __shared__ float ssc[FEAT], sof[FEAT];
  int M=hi[10];
  if(threadIdx.x<FEAT){
    double Md=(double)(M>0?M:1);
    double mu=(double)bnsum[threadIdx.x]/Md;
    double var=(double)bnsq[threadIdx.x]/Md-mu*mu;
    if(var<0.0) var=0.0;
    float sc=(float)(1.0/sqrt(var+(double)EPSC))*bng[threadIdx.x];
    ssc[threadIdx.x]=sc;
    sof[threadIdx.x]=bnb[threadIdx.x]-(float)mu*sc;
  }
  __syncthreads();
  int total=M*16;
  for(int i=blockIdx.x*blockDim.x+threadIdx.x; i<total; i+=gridDim.x*blockDim.x){
    int c0=(i&15)*8;
    short8 yv=*(const short8*)(ybf+(size_t)i*8);
    short8 rv=*(const short8*)(rbf+(size_t)i*8);
    short8 ov;
    #pragma unroll
    for(int j=0;j<8;j++){
      float v=bf2f((unsigned short)yv[j]);
      float r=bf2f((unsigned short)rv[j]);
      ov[j]=(short)f2bf(fmaxf(fmaf(v,ssc[c0+j],sof[c0+j])+r,0.f));
    }
    *(short8*)(xbf+(size_t)i*8)=ov;
    if(!LAST) *(short8*)(rbf+(size_t)i*8)=ov;
  }
}

// ---------------- output head: MFMA GEMM1 (128->64) + scalar GEMM2 (64->14) ----------------
__global__ __launch_bounds__(256) void k_headm(const unsigned short* __restrict__ X, const int* __restrict__ inv,
    const float* __restrict__ w1, const float* __restrict__ b1,
    const float* __restrict__ w2, const float* __restrict__ b2, float* __restrict__ out){
  __shared__ unsigned short w1t[HIDN*FEAT];
  __shared__ float hbuf[FEAT*65];
  __shared__ float w2s[HIDN*GD];
  __shared__ float b1s[HIDN];
  int tid=threadIdx.x;
  for(int e=tid;e<HIDN*FEAT;e+=256){
    int o=e>>7, in=e&127;
    int sub=in>>3, j=in&7;
    w1t[(o*16+(sub^(o&15)))*8+j]=f2bf(w1[in*HIDN+o]);
  }
  for(int i=tid;i<HIDN*GD;i+=256) w2s[i]=w2[i];
  if(tid<HIDN) b1s[tid]=b1[tid];
  __syncthreads();
  int p0=blockIdx.x*128;
  int w=tid>>6, l=tid&63;
  int g=l>>4, ln=l&15;
  int rbase=w*32;
  int gr[2];
  #pragma unroll
  for(int rt=0;rt<2;rt++) gr[rt]=inv[p0+rbase+rt*16+ln];
  f32x4 acc[2][4];
  #pragma unroll
  for(int rt=0;rt<2;rt++)
    #pragma unroll
    for(int nt=0;nt<4;nt++)
      acc[rt][nt]=(f32x4){0.f,0.f,0.f,0.f};
  #pragma unroll
  for(int ks=0;ks<4;ks++){
    short8 a[2];
    #pragma unroll
    for(int rt=0;rt<2;rt++)
      a[rt]=*(const short8*)(X+(size_t)gr[rt]*FEAT+ks*32+g*8);
    #pragma unroll
    for(int nt=0;nt<4;nt++){
      int col=nt*16+ln;
      short8 b=*(const short8*)&w1t[(size_t)(col*16+((ks*4+g)^(col&15)))*8];
      #pragma unroll
      for(int rt=0;rt<2;rt++)
        acc[rt][nt]=__builtin_amdgcn_mfma_f32_16x16x32_bf16(a[rt],b,acc[rt][nt],0,0,0);
    }
  }
  #pragma unroll
  for(int rt=0;rt<2;rt++){
    #pragma unroll
    for(int nt=0;nt<4;nt++){
      int col=nt*16+ln;
      float bb=b1s[col];
      #pragma unroll
      for(int r=0;r<4;r++){
        int row=rbase+rt*16+g*4+r;
        hbuf[row*65+col]=fmaxf(acc[rt][nt][r]+bb,0.f);
      }
    }
  }
  __syncthreads();
  int row=tid>>1, o0=(tid&1)*7;
  float a2[7];
  #pragma unroll
  for(int oi=0;oi<7;oi++) a2[oi]=b2[o0+oi];
  const float* hr=&hbuf[row*65];
  for(int j=0;j<HIDN;j++){
    float hv=hr[j];
    const float* wr=&w2s[j*GD+o0];
    #pragma unroll
    for(int oi=0;oi<7;oi++) a2[oi]=fmaf(hv,wr[oi],a2[oi]);
  }
  float* op=out+(size_t)(p0+row)*GD+o0;
  #pragma unroll
  for(int oi=0;oi<7;oi++) op[oi]=a2[oi];
}

extern "C" void kernel_launch(void* const* d_in, const int* in_sizes, int n_in,
                              void* d_out, int out_size, void* d_ws, size_t ws_size,
                              hipStream_t stream) {
  if(ws_size < WS_NEED) return;
  const float* gp  =(const float*)d_in[0];
  const float* psin=(const float*)d_in[1];
  const float* w_in=(const float*)d_in[2];
  const float* b_in=(const float*)d_in[3];
  const float* ln_g=(const float*)d_in[4];
  const float* ln_b=(const float*)d_in[5];
  const float* cw1 =(const float*)d_in[6];
  const float* bn1g=(const float*)d_in[7];
  const float* bn1b=(const float*)d_in[8];
  const float* cw2 =(const float*)d_in[9];
  const float* bn2g=(const float*)d_in[10];
  const float* bn2b=(const float*)d_in[11];
  const float* wh1 =(const float*)d_in[12];
  const float* bh1 =(const float*)d_in[13];
  const float* wh2 =(const float*)d_in[14];
  const float* bh2 =(const float*)d_in[15];
  float* out=(float*)d_out;

  char* ws=(char*)d_ws;
  int*    hi    =(int*)(ws+OFF_HDR);
  float*  hf    =(float*)(ws+OFF_HDR);
  float*  bnsA  =(float*)(ws+OFF_BNS);
  float*  bnqA  =(float*)(ws+OFF_BNQ);
  double* redp  =(double*)(ws+OFF_RED);
  int*    hist  =(int*)(ws+OFF_HIST);
  int*    tkeys =(int*)(ws+OFF_TKEY);
  int*    tslot =(int*)(ws+OFF_TSLOT);
  int*    tidx  =(int*)(ws+OFF_TIDX);
  int*    inv   =(int*)(ws+OFF_INV);
  int*    voxh  =(int*)(ws+OFF_VOXH);
  int*    cnt   =(int*)(ws+OFF_CNT);
  int*    vc    =(int*)(ws+OFF_VC);
  int*    nbr   =(int*)(ws+OFF_NBR);
  unsigned short* wt =(unsigned short*)(ws+OFF_WT);
  unsigned short* xbf=(unsigned short*)(ws+OFF_XBF);
  float*  vf    =(float*)(ws+OFF_VF);
  unsigned short* ybuf=(unsigned short*)(ws+OFF_YB);
  unsigned short* rbf =(unsigned short*)(ws+OFF_RBF);

  hipMemsetAsync(tkeys,0xFF,(size_t)TSIZE*4,stream);
  hipMemsetAsync(vf,0,(size_t)N_PTSC*FEAT*4,stream);
  hipMemsetAsync(cnt,0,(size_t)N_PTSC*4,stream);
  hipMemsetAsync(hist,0,(size_t)NBUCK*4,stream);
  hipMemsetAsync(ws+OFF_BNS,0,4096,stream);

  k_red1<<<RED_BLOCKS,256,0,stream>>>(gp,psin,redp);
  k_red2<<<1,256,0,stream>>>(redp,hi,hf);
  k_vc<<<256,256,0,stream>>>(gp,psin,hf,hi,vc);
  k_grid<<<1,64,0,stream>>>(hi);
  k_hash<<<N_PTSC/256,256,0,stream>>>(vc,hi,tkeys,tidx);
  k_hist<<<TSIZE/256,256,0,stream>>>(tkeys,hi,hist);
  k_scan<<<1,256,0,stream>>>(hist,hi);
  k_slot2<<<TSIZE/256,256,0,stream>>>(tkeys,hi,hist,tslot,voxh);
  k_wprep<<<(4*27*FEAT*FEAT)/256,256,0,stream>>>(cw1,cw2,wt);
  k_pool<<<N_PTSC/4,256,0,stream>>>(gp,w_in,b_in,ln_g,ln_b,tidx,tslot,inv,cnt,vf);
  k_div<<<2048,256,0,stream>>>(vf,xbf,rbf,cnt,hi);
  k_nbr<<<2048,256,0,stream>>>(voxh,tkeys,tslot,hi,nbr);

  for(int l=0;l<2;l++){
    int j0=l*2, j1=l*2+1;
    k_conv<<<NB_CONV,512,0,stream>>>(xbf,ybuf,wt+((size_t)j0*27)*FEAT*FEAT,nbr,hi,bnsA+j0*FEAT,bnqA+j0*FEAT);
    k_bnapply_relu<<<2048,256,0,stream>>>(ybuf,xbf,bnsA+j0*FEAT,bnqA+j0*FEAT,bn1g+(size_t)l*FEAT,bn1b+(size_t)l*FEAT,hi);

    k_conv<<<NB_CONV,512,0,stream>>>(xbf,ybuf,wt+((size_t)j1*27)*FEAT*FEAT,nbr,hi,bnsA+j1*FEAT,bnqA+j1*FEAT);
    if(l==0)
      k_bnapply_res<0><<<2048,256,0,stream>>>(ybuf,rbf,xbf,bnsA+j1*FEAT,bnqA+j1*FEAT,bn2g+(size_t)l*FEAT,bn2b+(size_t)l*FEAT,hi);
    else
      k_bnapply_res<1><<<2048,256,0,stream>>>(ybuf,rbf,xbf,bnsA+j1*FEAT,bnqA+j1*FEAT,bn2g+(size_t)l*FEAT,bn2b+(size_t)l*FEAT,hi);
  }

  k_headm<<<N_PTSC/128,256,0,stream>>>(xbf,inv,wh1,bh1,wh2,bh2,out);
}